// Round 4
// baseline (285.583 us; speedup 1.0000x reference)
//
#include <hip/hip_runtime.h>

#define DIM 512

// sign = (-1)^par as a float, branchless
__device__ __forceinline__ float sgnf(int par) {
    return __int_as_float(0x3F800000u | ((unsigned)par << 31));
}

// One 64-lane wave per state. idx = lane*8 + j  (lane = idx bits 8..3, j = bits 2..0).
// Computes E = (1/512) * sum_idx s[idx] * Re( conj(z[idx]) * z[idx^0x82] ),
// z = unnormalized WHT of d1[idx]*psi[idx].
__global__ __launch_bounds__(256) void qcnn9_kernel(
    const float* __restrict__ sr, const float* __restrict__ si,
    float* __restrict__ out, int bsz)
{
    const int tid   = blockIdx.x * blockDim.x + threadIdx.x;
    const int state = tid >> 6;
    const int lane  = threadIdx.x & 63;
    if (state >= bsz) return;

    const float* __restrict__ pr = sr + (size_t)state * DIM + lane * 8;
    const float* __restrict__ pi = si + (size_t)state * DIM + lane * 8;

    float zr[8], zi[8];
    {   // coalesced float4 loads (16B aligned: offset = 32B * lane)
        float4 r0 = *reinterpret_cast<const float4*>(pr);
        float4 r1 = *reinterpret_cast<const float4*>(pr + 4);
        float4 i0 = *reinterpret_cast<const float4*>(pi);
        float4 i1 = *reinterpret_cast<const float4*>(pi + 4);
        zr[0]=r0.x; zr[1]=r0.y; zr[2]=r0.z; zr[3]=r0.w;
        zr[4]=r1.x; zr[5]=r1.y; zr[6]=r1.z; zr[7]=r1.w;
        zi[0]=i0.x; zi[1]=i0.y; zi[2]=i0.z; zi[3]=i0.w;
        zi[4]=i1.x; zi[5]=i1.y; zi[6]=i1.z; zi[7]=i1.w;
    }

    const int base = lane * 8;

    // D1 diagonal: parity of the 10 conv-layer CZ pair products.
    // adjacent wire pairs -> bits of idx&(idx>>1) (mask 0xFF);
    // wire pairs (1,4),(4,7) -> bits 4,1 of idx&(idx>>3) (mask 0x12).
    #pragma unroll
    for (int j = 0; j < 8; ++j) {
        int idx = base + j;
        int t = idx & (idx >> 1);
        int u = idx & (idx >> 3);
        int par = __popc((t & 0xFF) | ((u & 0x12) << 8)) & 1;
        float s = sgnf(par);
        zr[j] *= s; zi[j] *= s;
    }

    // WHT: 3 register-local stages (idx bits 0..2)
    #pragma unroll
    for (int b = 0; b < 3; ++b) {
        const int m = 1 << b;
        #pragma unroll
        for (int j = 0; j < 8; ++j) {
            if (!(j & m)) {
                const int k = j | m;
                float ar = zr[j], ai = zi[j];
                float br = zr[k], bi = zi[k];
                zr[j] = ar + br; zi[j] = ai + bi;
                zr[k] = ar - br; zi[k] = ai - bi;
            }
        }
    }

    // WHT: 6 cross-lane stages (idx bits 3..8 = lane bits 0..5)
    #pragma unroll
    for (int b = 0; b < 6; ++b) {
        const int m = 1 << b;
        const float s = (lane & m) ? -1.0f : 1.0f;
        #pragma unroll
        for (int j = 0; j < 8; ++j) {
            float tr = __shfl_xor(zr[j], m, 64);
            float ti = __shfl_xor(zi[j], m, 64);
            zr[j] = fmaf(s, zr[j], tr);   // bit=0: z+t ; bit=1: t-z
            zi[j] = fmaf(s, zi[j], ti);
        }
    }

    // Readout: pair idx with idx^0x82 (lane^16, reg j^2),
    // sign s[idx] = bit6 ^ bit4 ^ bit2 ^ (bit8&bit6) ^ (bit0&bit2)
    float acc = 0.0f;
    #pragma unroll
    for (int j = 0; j < 8; ++j) {
        float prr = __shfl_xor(zr[j ^ 2], 16, 64);
        float pii = __shfl_xor(zi[j ^ 2], 16, 64);
        int idx = base + j;
        int par = ((idx >> 6) ^ (idx >> 4) ^ (idx >> 2)
                   ^ ((idx >> 8) & (idx >> 6))
                   ^ (idx & (idx >> 2))) & 1;
        float s = sgnf(par);
        float term = fmaf(zr[j], prr, zi[j] * pii);
        acc = fmaf(s, term, acc);
    }

    // reduce across the 64-lane wave
    #pragma unroll
    for (int m = 32; m >= 1; m >>= 1)
        acc += __shfl_xor(acc, m, 64);

    if (lane == 0) out[state] = acc * (1.0f / 512.0f);
}

extern "C" void kernel_launch(void* const* d_in, const int* in_sizes, int n_in,
                              void* d_out, int out_size, void* d_ws, size_t ws_size,
                              hipStream_t stream) {
    const float* sr = (const float*)d_in[0];
    const float* si = (const float*)d_in[1];
    // d_in[2] = n_shots (<=0 -> analytical path) : unused
    float* out = (float*)d_out;
    const int bsz = in_sizes[0] / DIM;

    const int threads = 256;                       // 4 waves / block
    const int blocks  = (bsz * 64 + threads - 1) / threads;
    qcnn9_kernel<<<blocks, threads, 0, stream>>>(sr, si, out, bsz);
}

// Round 10
// 270.813 us; speedup vs baseline: 1.0545x; 1.0545x over previous
//
#include <hip/hip_runtime.h>

#define DIM 512

// sign = (-1)^par as a float, branchless
__device__ __forceinline__ float sgnf(int par) {
    return __int_as_float(0x3F800000u | ((unsigned)par << 31));
}

// ds_swizzle lane-xor within 32-lane groups: pattern = (xor<<10) | 0x1F
template<int PAT>
__device__ __forceinline__ float swz(float x) {
    return __int_as_float(__builtin_amdgcn_ds_swizzle(__float_as_int(x), PAT));
}
// DPP quad_perm lane-xor within quads (VALU pipe, no DS latency)
template<int CTRL>
__device__ __forceinline__ float dppmov(float x) {
    return __int_as_float(__builtin_amdgcn_mov_dpp(__float_as_int(x), CTRL, 0xF, 0xF, true));
}
__device__ __forceinline__ float sx32(float x) { return __shfl_xor(x, 32, 64); }

// One 64-lane wave handles TWO consecutive states. idx = lane*8 + j.
// E = (1/512) * sum_idx s[idx] * Re( conj(z[idx]) * z[idx^0x82] ),
// z = unnormalized WHT of d1[idx]*psi[idx].
__global__ __launch_bounds__(256) void qcnn9_kernel(
    const float* __restrict__ sr, const float* __restrict__ si,
    float* __restrict__ out, int bsz)
{
    const int wid  = (blockIdx.x * blockDim.x + threadIdx.x) >> 6;
    const int lane = threadIdx.x & 63;
    const int s0   = wid * 2;
    if (s0 >= bsz) return;
    const bool hasB = (s0 + 1) < bsz;

    const size_t offA = (size_t)s0 * DIM + lane * 8;
    const size_t offB = offA + (hasB ? DIM : 0);   // duplicate A if odd tail

    // Issue all 8 independent float4 loads up front (latency overlap)
    float4 ar0 = *reinterpret_cast<const float4*>(sr + offA);
    float4 ar1 = *reinterpret_cast<const float4*>(sr + offA + 4);
    float4 ai0 = *reinterpret_cast<const float4*>(si + offA);
    float4 ai1 = *reinterpret_cast<const float4*>(si + offA + 4);
    float4 br0 = *reinterpret_cast<const float4*>(sr + offB);
    float4 br1 = *reinterpret_cast<const float4*>(sr + offB + 4);
    float4 bi0 = *reinterpret_cast<const float4*>(si + offB);
    float4 bi1 = *reinterpret_cast<const float4*>(si + offB + 4);

    float z0r[8] = {ar0.x,ar0.y,ar0.z,ar0.w, ar1.x,ar1.y,ar1.z,ar1.w};
    float z0i[8] = {ai0.x,ai0.y,ai0.z,ai0.w, ai1.x,ai1.y,ai1.z,ai1.w};
    float z1r[8] = {br0.x,br0.y,br0.z,br0.w, br1.x,br1.y,br1.z,br1.w};
    float z1i[8] = {bi0.x,bi0.y,bi0.z,bi0.w, bi1.x,bi1.y,bi1.z,bi1.w};

    const int base = lane * 8;

    // D1 diagonal (function of idx only -> shared by both states):
    // adjacent wire-pair CZs -> bits of idx&(idx>>1)&0xFF;
    // CZ(1,4),CZ(4,7) -> bits 4,1 of idx&(idx>>3).
    #pragma unroll
    for (int j = 0; j < 8; ++j) {
        int idx = base + j;
        int t = idx & (idx >> 1);
        int u = idx & (idx >> 3);
        float s = sgnf(__popc((t & 0xFF) | ((u & 0x12) << 8)) & 1);
        z0r[j] *= s; z0i[j] *= s; z1r[j] *= s; z1i[j] *= s;
    }

    // WHT: 3 register-local stages (idx bits 0..2), both states
    #pragma unroll
    for (int b = 0; b < 3; ++b) {
        const int m = 1 << b;
        #pragma unroll
        for (int j = 0; j < 8; ++j) {
            if (!(j & m)) {
                const int k = j | m;
                float x, y;
                x = z0r[j]; y = z0r[k]; z0r[j] = x + y; z0r[k] = x - y;
                x = z0i[j]; y = z0i[k]; z0i[j] = x + y; z0i[k] = x - y;
                x = z1r[j]; y = z1r[k]; z1r[j] = x + y; z1r[k] = x - y;
                x = z1i[j]; y = z1i[k]; z1i[j] = x + y; z1i[k] = x - y;
            }
        }
    }

    // WHT: 6 cross-lane stages (idx bits 3..8 = lane bits 0..5).
    // fmaf(s, z, t): lane-bit=0 -> z+t ; =1 -> t-z.
#define XSTAGE(MBIT, XF)                                                      \
    {                                                                         \
        const float s = (lane & (MBIT)) ? -1.0f : 1.0f;                       \
        _Pragma("unroll")                                                     \
        for (int j = 0; j < 8; ++j) {                                         \
            float t0r = XF(z0r[j]); float t0i = XF(z0i[j]);                   \
            float t1r = XF(z1r[j]); float t1i = XF(z1i[j]);                   \
            z0r[j] = fmaf(s, z0r[j], t0r); z0i[j] = fmaf(s, z0i[j], t0i);     \
            z1r[j] = fmaf(s, z1r[j], t1r); z1i[j] = fmaf(s, z1i[j], t1i);     \
        }                                                                     \
    }
    XSTAGE(1,  dppmov<0xB1>)   // quad_perm [1,0,3,2] = lane^1  (VALU)
    XSTAGE(2,  dppmov<0x4E>)   // quad_perm [2,3,0,1] = lane^2  (VALU)
    XSTAGE(4,  swz<0x101F>)    // ds_swizzle xor4
    XSTAGE(8,  swz<0x201F>)    // ds_swizzle xor8
    XSTAGE(16, swz<0x401F>)    // ds_swizzle xor16
    XSTAGE(32, sx32)           // ds_bpermute cross-half
#undef XSTAGE

    // Readout: pair idx with idx^0x82 (lane^16, reg j^2),
    // sign s[idx] = bit6 ^ bit4 ^ bit2 ^ (bit8&bit6) ^ (bit0&bit2)
    float acc0 = 0.0f, acc1 = 0.0f;
    #pragma unroll
    for (int j = 0; j < 8; ++j) {
        float p0r = swz<0x401F>(z0r[j ^ 2]);
        float p0i = swz<0x401F>(z0i[j ^ 2]);
        float p1r = swz<0x401F>(z1r[j ^ 2]);
        float p1i = swz<0x401F>(z1i[j ^ 2]);
        int idx = base + j;
        int par = ((idx >> 6) ^ (idx >> 4) ^ (idx >> 2)
                   ^ ((idx >> 8) & (idx >> 6))
                   ^ (idx & (idx >> 2))) & 1;
        float s = sgnf(par);
        acc0 = fmaf(s, fmaf(z0r[j], p0r, z0i[j] * p0i), acc0);
        acc1 = fmaf(s, fmaf(z1r[j], p1r, z1i[j] * p1i), acc1);
    }

    // 64-lane reduction, both states interleaved for ILP
    { float t0 = dppmov<0xB1>(acc0),  t1 = dppmov<0xB1>(acc1);  acc0 += t0; acc1 += t1; }
    { float t0 = dppmov<0x4E>(acc0),  t1 = dppmov<0x4E>(acc1);  acc0 += t0; acc1 += t1; }
    { float t0 = swz<0x101F>(acc0),   t1 = swz<0x101F>(acc1);   acc0 += t0; acc1 += t1; }
    { float t0 = swz<0x201F>(acc0),   t1 = swz<0x201F>(acc1);   acc0 += t0; acc1 += t1; }
    { float t0 = swz<0x401F>(acc0),   t1 = swz<0x401F>(acc1);   acc0 += t0; acc1 += t1; }
    { float t0 = sx32(acc0),          t1 = sx32(acc1);          acc0 += t0; acc1 += t1; }

    if (lane == 0) {
        if (hasB) {
            *reinterpret_cast<float2*>(out + s0) =
                make_float2(acc0 * (1.0f / 512.0f), acc1 * (1.0f / 512.0f));
        } else {
            out[s0] = acc0 * (1.0f / 512.0f);
        }
    }
}

extern "C" void kernel_launch(void* const* d_in, const int* in_sizes, int n_in,
                              void* d_out, int out_size, void* d_ws, size_t ws_size,
                              hipStream_t stream) {
    const float* sr = (const float*)d_in[0];
    const float* si = (const float*)d_in[1];
    // d_in[2] = n_shots (<=0 -> analytical path) : unused
    float* out = (float*)d_out;
    const int bsz = in_sizes[0] / DIM;

    const int threads = 256;                        // 4 waves / block
    const int nwaves  = (bsz + 1) / 2;              // 2 states per wave
    const int blocks  = (nwaves * 64 + threads - 1) / threads;
    qcnn9_kernel<<<blocks, threads, 0, stream>>>(sr, si, out, bsz);
}